// Round 2
// baseline (985.494 us; speedup 1.0000x reference)
//
#include <hip/hip_runtime.h>
#include <cstdint>
#include <cstddef>

typedef __bf16 bf16x8 __attribute__((ext_vector_type(8)));
typedef float floatx4 __attribute__((ext_vector_type(4)));

#define DEV static __device__ __forceinline__

DEV float bf2f(uint16_t u) {
    union { uint32_t i; float f; } x; x.i = ((uint32_t)u) << 16; return x.f;
}
DEV uint16_t f2bf(float f) {
    uint32_t u = __float_as_uint(f);
    uint32_t r = (u + 0x7FFFu + ((u >> 16) & 1u)) >> 16;   // RNE
    return (uint16_t)r;
}

union U16x8 { uint16_t h[8]; uint4 u; };

// ---------------- problem constants ----------------
constexpr int DIMC  = 384;
constexpr int HEADS = 12;
constexpr int HD    = 32;      // head dim
constexpr int IMH   = 56, IMW = 56;
constexpr int NTOK  = IMH * IMW;        // 3136
constexpr int BATCH = 16;
constexpr int MTOT  = BATCH * NTOK;     // 50176

// ---------------- GEMM: C[M,N] = A[M,K] @ B[K,N] (+bias) ----------
// A fp32 (converted to bf16 in staging), B fp32 (converted in staging),
// C bf16 (CF32=false) or fp32 (CF32=true).
constexpr int BM = 128, BN = 128, BK = 32;
constexpr int LDT = BK + 8;  // padded LDS row stride (elements)

template<bool CF32>
__global__ __launch_bounds__(256) void gemm_f32in(const float* __restrict__ A,
                                                  const float* __restrict__ B,
                                                  const float* __restrict__ bias,
                                                  void* __restrict__ Cptr,
                                                  int M, int K, int N)
{
    __shared__ __align__(16) uint16_t sA[BM * LDT];
    __shared__ __align__(16) uint16_t sB[BN * LDT];

    const int t    = threadIdx.x;
    const int bm   = blockIdx.x, bn = blockIdx.y;
    const int wave = t >> 6, lane = t & 63;
    const int wm   = (wave >> 1) * 64, wn = (wave & 1) * 64;
    const int lr   = lane & 15, quad = lane >> 4;

    const int rowA = t >> 2;          // 0..63
    const int colA = (t & 3) * 8;     // 0,8,16,24
    const int kB   = t >> 4;          // 0..15
    const int nB   = (t & 15) * 8;    // 0..120

    floatx4 acc[4][4] = {};

    for (int k0 = 0; k0 < K; k0 += BK) {
        __syncthreads();
        // ---- stage A tile (row-major [BM][BK], fp32 -> bf16) ----
        #pragma unroll
        for (int half = 0; half < 2; ++half) {
            int r = rowA + half * 64;
            const float* src = A + (size_t)(bm * BM + r) * K + k0 + colA;
            float4 f0 = *(const float4*)src;
            float4 f1 = *(const float4*)(src + 4);
            U16x8 tmp;
            tmp.h[0] = f2bf(f0.x); tmp.h[1] = f2bf(f0.y);
            tmp.h[2] = f2bf(f0.z); tmp.h[3] = f2bf(f0.w);
            tmp.h[4] = f2bf(f1.x); tmp.h[5] = f2bf(f1.y);
            tmp.h[6] = f2bf(f1.z); tmp.h[7] = f2bf(f1.w);
            *(uint4*)&sA[r * LDT + colA] = tmp.u;
        }
        // ---- stage B tile transposed (LDS [BN][BK], fp32 -> bf16) ----
        #pragma unroll
        for (int half = 0; half < 2; ++half) {
            int k = kB + half * 16;
            const float* src = B + (size_t)(k0 + k) * N + bn * BN + nB;
            float4 f0 = *(const float4*)src;
            float4 f1 = *(const float4*)(src + 4);
            uint16_t hv[8];
            hv[0] = f2bf(f0.x); hv[1] = f2bf(f0.y);
            hv[2] = f2bf(f0.z); hv[3] = f2bf(f0.w);
            hv[4] = f2bf(f1.x); hv[5] = f2bf(f1.y);
            hv[6] = f2bf(f1.z); hv[7] = f2bf(f1.w);
            #pragma unroll
            for (int i = 0; i < 8; ++i) sB[(nB + i) * LDT + k] = hv[i];
        }
        __syncthreads();

        bf16x8 af[4], bfr[4];
        #pragma unroll
        for (int mt = 0; mt < 4; ++mt)
            af[mt] = *(const bf16x8*)&sA[(wm + mt * 16 + lr) * LDT + quad * 8];
        #pragma unroll
        for (int nt = 0; nt < 4; ++nt)
            bfr[nt] = *(const bf16x8*)&sB[(wn + nt * 16 + lr) * LDT + quad * 8];
        #pragma unroll
        for (int mt = 0; mt < 4; ++mt)
            #pragma unroll
            for (int nt = 0; nt < 4; ++nt)
                acc[mt][nt] = __builtin_amdgcn_mfma_f32_16x16x32_bf16(
                    af[mt], bfr[nt], acc[mt][nt], 0, 0, 0);
    }

    // ---- epilogue: C/D layout col=lane&15, row=quad*4+reg ----
    #pragma unroll
    for (int mt = 0; mt < 4; ++mt) {
        #pragma unroll
        for (int nt = 0; nt < 4; ++nt) {
            int gc = bn * BN + wn + nt * 16 + lr;
            float bv = bias ? bias[gc] : 0.0f;
            int gr0 = bm * BM + wm + mt * 16 + quad * 4;
            #pragma unroll
            for (int i = 0; i < 4; ++i) {
                if constexpr (CF32) {
                    ((float*)Cptr)[(size_t)(gr0 + i) * N + gc] = acc[mt][nt][i] + bv;
                } else {
                    ((uint16_t*)Cptr)[(size_t)(gr0 + i) * N + gc] = f2bf(acc[mt][nt][i] + bv);
                }
            }
        }
    }
}

// ---------------- windowed attention: one 64-thread block per (b,win,head) --
__global__ __launch_bounds__(64) void attn_kernel(const uint16_t* __restrict__ qkv,
                                                  float* __restrict__ y)
{
    const int bid = blockIdx.x;          // b*768 + w*12 + h
    const int h = bid % HEADS;
    const int w = (bid / HEADS) % 64;
    const int b = bid / (HEADS * 64);
    const int wy = w >> 3, wx = w & 7;

    __shared__ float sq[49 * 32], sk[49 * 32], sv[49 * 32];
    __shared__ float sS[49 * 49];

    const int t = threadIdx.x;

    // load q,k,v (fp32 in LDS)
    for (int e = t; e < 49 * 32; e += 64) {
        int i = e >> 5, d = e & 31;
        int py = i / 7, px = i % 7;
        int n = (wy * 7 + py) * IMW + wx * 7 + px;
        size_t base = (size_t)(b * NTOK + n) * (3 * DIMC) + h * HD + d;
        sq[e] = bf2f(qkv[base]);
        sk[e] = bf2f(qkv[base + DIMC]);
        sv[e] = bf2f(qkv[base + 2 * DIMC]);
    }
    __syncthreads();

    const float scale = 0.17677669529663687f;  // 32^-0.5
    for (int idx = t; idx < 49 * 49; idx += 64) {
        int i = idx / 49, j = idx % 49;
        float acc = 0.0f;
        #pragma unroll
        for (int d = 0; d < 32; ++d) acc += sq[i * 32 + d] * sk[j * 32 + d];
        sS[idx] = acc * scale;
    }
    __syncthreads();

    if (t < 49) {
        float m = -1e30f;
        for (int j = 0; j < 49; ++j) m = fmaxf(m, sS[t * 49 + j]);
        float s = 0.0f;
        for (int j = 0; j < 49; ++j) {
            float e = __expf(sS[t * 49 + j] - m);
            sS[t * 49 + j] = e;
            s += e;
        }
        float inv = 1.0f / s;
        for (int j = 0; j < 49; ++j) sS[t * 49 + j] *= inv;
    }
    __syncthreads();

    for (int e = t; e < 49 * 32; e += 64) {
        int i = e >> 5, d = e & 31;
        float acc = 0.0f;
        #pragma unroll
        for (int j = 0; j < 49; ++j) acc += sS[i * 49 + j] * sv[j * 32 + d];
        int py = i / 7, px = i % 7;
        int n = (wy * 7 + py) * IMW + wx * 7 + px;
        y[(size_t)(b * NTOK + n) * DIMC + h * HD + d] = acc;
    }
}

// ---------------- depthwise 3x3 conv on v, accumulate into y ----------------
__global__ __launch_bounds__(256) void conv_kernel(const uint16_t* __restrict__ qkv,
                                                   const float* __restrict__ wconv,
                                                   const float* __restrict__ bconv,
                                                   float* __restrict__ y)
{
    size_t idx = (size_t)blockIdx.x * 256 + threadIdx.x;  // b*N*C exact
    int c   = (int)(idx % DIMC);
    int rem = (int)(idx / DIMC);      // b*NTOK + n
    int n   = rem % NTOK;
    int b   = rem / NTOK;
    int y0 = n / IMW, x0 = n % IMW;

    float acc = bconv[c];
    #pragma unroll
    for (int ky = 0; ky < 3; ++ky) {
        int yy = y0 + ky - 1;
        if (yy < 0 || yy >= IMH) continue;
        #pragma unroll
        for (int kx = 0; kx < 3; ++kx) {
            int xx = x0 + kx - 1;
            if (xx < 0 || xx >= IMW) continue;
            float vv = bf2f(qkv[(size_t)(b * NTOK + yy * IMW + xx) * (3 * DIMC) + 2 * DIMC + c]);
            float wv = wconv[(ky * 3 + kx) * DIMC + c];
            acc += vv * wv;
        }
    }
    y[idx] += acc;
}

// ---------------- launch ----------------
extern "C" void kernel_launch(void* const* d_in, const int* in_sizes, int n_in,
                              void* d_out, int out_size, void* d_ws, size_t ws_size,
                              hipStream_t stream)
{
    const float* x      = (const float*)d_in[0];
    const float* w_qkv  = (const float*)d_in[1];
    const float* w_proj = (const float*)d_in[2];
    const float* b_proj = (const float*)d_in[3];
    const float* w_conv = (const float*)d_in[4];
    const float* b_conv = (const float*)d_in[5];
    float* out = (float*)d_out;

    uint16_t* qkv = (uint16_t*)d_ws;                                   // 50176*1152 bf16
    float*    y   = (float*)((char*)d_ws + (size_t)MTOT * 1152 * 2);   // 50176*384 fp32

    // 1) qkv = x @ w_qkv          (M=50176, K=384, N=1152), bf16 out
    gemm_f32in<false><<<dim3(MTOT / BM, 1152 / BN), 256, 0, stream>>>(
        x, w_qkv, nullptr, qkv, MTOT, DIMC, 3 * DIMC);

    // 2) windowed attention -> y (fp32)
    attn_kernel<<<dim3(BATCH * 64 * HEADS), 64, 0, stream>>>(qkv, y);

    // 3) depthwise conv on v, y += v_lim
    conv_kernel<<<dim3((MTOT * DIMC) / 256), 256, 0, stream>>>(qkv, w_conv, b_conv, y);

    // 4) out = y @ w_proj + b_proj (M=50176, K=384, N=384), fp32 out
    gemm_f32in<true><<<dim3(MTOT / BM, DIMC / BN), 256, 0, stream>>>(
        y, w_proj, b_proj, out, MTOT, DIMC, DIMC);
}

// Round 3
// 616.713 us; speedup vs baseline: 1.5980x; 1.5980x over previous
//
#include <hip/hip_runtime.h>
#include <cstdint>
#include <cstddef>

typedef __bf16 bf16x8 __attribute__((ext_vector_type(8)));
typedef float floatx4 __attribute__((ext_vector_type(4)));

#define DEV static __device__ __forceinline__

DEV float bf2f(uint16_t u) {
    union { uint32_t i; float f; } x; x.i = ((uint32_t)u) << 16; return x.f;
}
DEV uint16_t f2bf(float f) {
    uint32_t u = __float_as_uint(f);
    uint32_t r = (u + 0x7FFFu + ((u >> 16) & 1u)) >> 16;   // RNE
    return (uint16_t)r;
}
DEV bf16x8 as_bf8(uint4 u) {
    union { uint4 u; bf16x8 b; } c; c.u = u; return c.b;
}

union U16x8 { uint16_t h[8]; uint4 u; };

// ---------------- problem constants ----------------
constexpr int DIMC  = 384;
constexpr int HEADS = 12;
constexpr int IMH   = 56, IMW = 56;
constexpr int NTOK  = IMH * IMW;        // 3136
constexpr int BATCH = 16;
constexpr int MTOT  = BATCH * NTOK;     // 50176
constexpr int QKVLD = 3 * DIMC;         // 1152

// ---------------- GEMM: C[M,N] = A[M,K] @ B[K,N] (+bias) ----------
constexpr int BM = 128, BN = 128, BK = 32;
constexpr int LDT = BK + 8;  // padded LDS row stride (elements)

template<bool CF32>
__global__ __launch_bounds__(256) void gemm_f32in(const float* __restrict__ A,
                                                  const float* __restrict__ B,
                                                  const float* __restrict__ bias,
                                                  void* __restrict__ Cptr,
                                                  int M, int K, int N)
{
    __shared__ __align__(16) uint16_t sA[BM * LDT];
    __shared__ __align__(16) uint16_t sB[BN * LDT];

    const int t    = threadIdx.x;
    const int bm   = blockIdx.x, bn = blockIdx.y;
    const int wave = t >> 6, lane = t & 63;
    const int wm   = (wave >> 1) * 64, wn = (wave & 1) * 64;
    const int lr   = lane & 15, quad = lane >> 4;

    const int rowA = t >> 2;          // 0..63
    const int colA = (t & 3) * 8;     // 0,8,16,24
    const int kB   = t >> 4;          // 0..15
    const int nB   = (t & 15) * 8;    // 0..120

    floatx4 acc[4][4] = {};

    for (int k0 = 0; k0 < K; k0 += BK) {
        __syncthreads();
        #pragma unroll
        for (int half = 0; half < 2; ++half) {
            int r = rowA + half * 64;
            const float* src = A + (size_t)(bm * BM + r) * K + k0 + colA;
            float4 f0 = *(const float4*)src;
            float4 f1 = *(const float4*)(src + 4);
            U16x8 tmp;
            tmp.h[0] = f2bf(f0.x); tmp.h[1] = f2bf(f0.y);
            tmp.h[2] = f2bf(f0.z); tmp.h[3] = f2bf(f0.w);
            tmp.h[4] = f2bf(f1.x); tmp.h[5] = f2bf(f1.y);
            tmp.h[6] = f2bf(f1.z); tmp.h[7] = f2bf(f1.w);
            *(uint4*)&sA[r * LDT + colA] = tmp.u;
        }
        #pragma unroll
        for (int half = 0; half < 2; ++half) {
            int k = kB + half * 16;
            const float* src = B + (size_t)(k0 + k) * N + bn * BN + nB;
            float4 f0 = *(const float4*)src;
            float4 f1 = *(const float4*)(src + 4);
            uint16_t hv[8];
            hv[0] = f2bf(f0.x); hv[1] = f2bf(f0.y);
            hv[2] = f2bf(f0.z); hv[3] = f2bf(f0.w);
            hv[4] = f2bf(f1.x); hv[5] = f2bf(f1.y);
            hv[6] = f2bf(f1.z); hv[7] = f2bf(f1.w);
            #pragma unroll
            for (int i = 0; i < 8; ++i) sB[(nB + i) * LDT + k] = hv[i];
        }
        __syncthreads();

        bf16x8 af[4], bfr[4];
        #pragma unroll
        for (int mt = 0; mt < 4; ++mt)
            af[mt] = *(const bf16x8*)&sA[(wm + mt * 16 + lr) * LDT + quad * 8];
        #pragma unroll
        for (int nt = 0; nt < 4; ++nt)
            bfr[nt] = *(const bf16x8*)&sB[(wn + nt * 16 + lr) * LDT + quad * 8];
        #pragma unroll
        for (int mt = 0; mt < 4; ++mt)
            #pragma unroll
            for (int nt = 0; nt < 4; ++nt)
                acc[mt][nt] = __builtin_amdgcn_mfma_f32_16x16x32_bf16(
                    af[mt], bfr[nt], acc[mt][nt], 0, 0, 0);
    }

    #pragma unroll
    for (int mt = 0; mt < 4; ++mt) {
        #pragma unroll
        for (int nt = 0; nt < 4; ++nt) {
            int gc = bn * BN + wn + nt * 16 + lr;
            float bv = bias ? bias[gc] : 0.0f;
            int gr0 = bm * BM + wm + mt * 16 + quad * 4;
            #pragma unroll
            for (int i = 0; i < 4; ++i) {
                if constexpr (CF32) {
                    ((float*)Cptr)[(size_t)(gr0 + i) * N + gc] = acc[mt][nt][i] + bv;
                } else {
                    ((uint16_t*)Cptr)[(size_t)(gr0 + i) * N + gc] = f2bf(acc[mt][nt][i] + bv);
                }
            }
        }
    }
}

// ---------------- MFMA windowed attention ----------------
// one wave per (b, window, head); 2 waves / 128-thread block.
// LDS per wave: P 64x72 bf16 + Vt 32x72 bf16 = 13,824 B
constexpr int PLD = 72;   // padded row stride (bf16 elems): b128 reads land 2-way on banks

__global__ __launch_bounds__(128) void attn_mfma(const uint16_t* __restrict__ qkv,
                                                 float* __restrict__ y)
{
    __shared__ uint16_t lds[2][(64 + 32) * PLD];

    const int wave = threadIdx.x >> 6;
    const int lane = threadIdx.x & 63;
    const int unit = blockIdx.x * 2 + wave;          // 0..12287
    const int h  = unit % HEADS;
    const int w  = (unit / HEADS) & 63;
    const int b  = unit / (HEADS * 64);
    const int wy = w >> 3, wx = w & 7;
    const int lr = lane & 15, quad = lane >> 4;

    uint16_t* Pbuf = lds[wave];
    uint16_t* Vt   = lds[wave] + 64 * PLD;

    // token row base in qkv for window position i, component which (0=q,1=k,2=v)
    auto rowbase = [&](int i, int which) -> const uint16_t* {
        int py = i / 7, px = i % 7;
        int n = (wy * 7 + py) * IMW + wx * 7 + px;
        return qkv + (size_t)(b * NTOK + n) * QKVLD + which * DIMC + h * 32;
    };

    // ---- load Q/K fragments straight from global (16B per lane per tile) ----
    uint4 qf[4], kf[4];
    #pragma unroll
    for (int tm = 0; tm < 4; ++tm) {
        int i = tm * 16 + lr;
        if (i < 49) {
            qf[tm] = *(const uint4*)(rowbase(i, 0) + quad * 8);
            kf[tm] = *(const uint4*)(rowbase(i, 1) + quad * 8);
        } else {
            qf[tm] = uint4{0, 0, 0, 0};
            kf[tm] = uint4{0, 0, 0, 0};
        }
    }

    // ---- stage V transposed into LDS: Vt[d][j] ----
    {
        int j = lane;
        uint16_t vrow[32];
        if (j < 49) {
            const uint16_t* vr = rowbase(j, 2);
            #pragma unroll
            for (int p = 0; p < 4; ++p) {
                U16x8 tmp; tmp.u = *(const uint4*)(vr + p * 8);
                #pragma unroll
                for (int q = 0; q < 8; ++q) vrow[p * 8 + q] = tmp.h[q];
            }
        } else {
            #pragma unroll
            for (int d = 0; d < 32; ++d) vrow[d] = 0;
        }
        #pragma unroll
        for (int d = 0; d < 32; ++d) Vt[d * PLD + j] = vrow[d];
    }

    // ---- S = Q @ K^T (64x64, K=32 in one MFMA step) ----
    floatx4 S[4][4] = {};
    #pragma unroll
    for (int tm = 0; tm < 4; ++tm)
        #pragma unroll
        for (int tn = 0; tn < 4; ++tn)
            S[tm][tn] = __builtin_amdgcn_mfma_f32_16x16x32_bf16(
                as_bf8(qf[tm]), as_bf8(kf[tn]), S[tm][tn], 0, 0, 0);

    // ---- softmax (no max-subtraction: |S*scale| is O(1) here) + P -> LDS ----
    const float scale = 0.17677669529663687f;  // 32^-0.5
    const bool v3 = (lr == 0);                 // col 48 is the only valid col in tile_n=3
    #pragma unroll
    for (int tm = 0; tm < 4; ++tm) {
        #pragma unroll
        for (int i = 0; i < 4; ++i) {
            float e0 = __expf(S[tm][0][i] * scale);
            float e1 = __expf(S[tm][1][i] * scale);
            float e2 = __expf(S[tm][2][i] * scale);
            float e3 = v3 ? __expf(S[tm][3][i] * scale) : 0.0f;
            float s = e0 + e1 + e2 + e3;
            #pragma unroll
            for (int d = 1; d < 16; d <<= 1) s += __shfl_xor(s, d);
            float inv = 1.0f / s;
            int row = tm * 16 + quad * 4 + i;
            Pbuf[row * PLD + lr]      = f2bf(e0 * inv);
            Pbuf[row * PLD + 16 + lr] = f2bf(e1 * inv);
            Pbuf[row * PLD + 32 + lr] = f2bf(e2 * inv);
            Pbuf[row * PLD + 48 + lr] = f2bf(e3 * inv);
        }
    }

    // ---- O = P @ V  (64x32, K=64 in two steps) ----
    floatx4 O[4][2] = {};
    #pragma unroll
    for (int kk = 0; kk < 2; ++kk) {
        bf16x8 pf[4], vf[2];
        #pragma unroll
        for (int tm = 0; tm < 4; ++tm)
            pf[tm] = *(const bf16x8*)&Pbuf[(tm * 16 + lr) * PLD + kk * 32 + quad * 8];
        #pragma unroll
        for (int tn = 0; tn < 2; ++tn)
            vf[tn] = *(const bf16x8*)&Vt[(tn * 16 + lr) * PLD + kk * 32 + quad * 8];
        #pragma unroll
        for (int tm = 0; tm < 4; ++tm)
            #pragma unroll
            for (int tn = 0; tn < 2; ++tn)
                O[tm][tn] = __builtin_amdgcn_mfma_f32_16x16x32_bf16(
                    pf[tm], vf[tn], O[tm][tn], 0, 0, 0);
    }

    // ---- write O rows (<49) to y, coalesced 16-lane fp32 stores ----
    #pragma unroll
    for (int tm = 0; tm < 4; ++tm) {
        #pragma unroll
        for (int i = 0; i < 4; ++i) {
            int r = tm * 16 + quad * 4 + i;
            if (r < 49) {
                int py = r / 7, px = r % 7;
                int n = (wy * 7 + py) * IMW + wx * 7 + px;
                float* dst = y + (size_t)(b * NTOK + n) * DIMC + h * 32;
                dst[lr]      = O[tm][0][i];
                dst[16 + lr] = O[tm][1][i];
            }
        }
    }
}

// ---------------- depthwise 3x3 conv on v, accumulate into y ----------------
__global__ __launch_bounds__(256) void conv_kernel(const uint16_t* __restrict__ qkv,
                                                   const float* __restrict__ wconv,
                                                   const float* __restrict__ bconv,
                                                   float* __restrict__ y)
{
    size_t idx = (size_t)blockIdx.x * 256 + threadIdx.x;  // b*N*C exact
    int c   = (int)(idx % DIMC);
    int rem = (int)(idx / DIMC);      // b*NTOK + n
    int n   = rem % NTOK;
    int b   = rem / NTOK;
    int y0 = n / IMW, x0 = n % IMW;

    float acc = bconv[c];
    #pragma unroll
    for (int ky = 0; ky < 3; ++ky) {
        int yy = y0 + ky - 1;
        if (yy < 0 || yy >= IMH) continue;
        #pragma unroll
        for (int kx = 0; kx < 3; ++kx) {
            int xx = x0 + kx - 1;
            if (xx < 0 || xx >= IMW) continue;
            float vv = bf2f(qkv[(size_t)(b * NTOK + yy * IMW + xx) * QKVLD + 2 * DIMC + c]);
            float wv = wconv[(ky * 3 + kx) * DIMC + c];
            acc += vv * wv;
        }
    }
    y[idx] += acc;
}

// ---------------- launch ----------------
extern "C" void kernel_launch(void* const* d_in, const int* in_sizes, int n_in,
                              void* d_out, int out_size, void* d_ws, size_t ws_size,
                              hipStream_t stream)
{
    const float* x      = (const float*)d_in[0];
    const float* w_qkv  = (const float*)d_in[1];
    const float* w_proj = (const float*)d_in[2];
    const float* b_proj = (const float*)d_in[3];
    const float* w_conv = (const float*)d_in[4];
    const float* b_conv = (const float*)d_in[5];
    float* out = (float*)d_out;

    uint16_t* qkv = (uint16_t*)d_ws;                                   // 50176*1152 bf16
    float*    y   = (float*)((char*)d_ws + (size_t)MTOT * QKVLD * 2);  // 50176*384 fp32

    // 1) qkv = x @ w_qkv          (M=50176, K=384, N=1152), bf16 out
    gemm_f32in<false><<<dim3(MTOT / BM, QKVLD / BN), 256, 0, stream>>>(
        x, w_qkv, nullptr, qkv, MTOT, DIMC, QKVLD);

    // 2) MFMA windowed attention -> y (fp32)
    attn_mfma<<<dim3(BATCH * 64 * HEADS / 2), 128, 0, stream>>>(qkv, y);

    // 3) depthwise conv on v, y += v_lim
    conv_kernel<<<dim3((MTOT * DIMC) / 256), 256, 0, stream>>>(qkv, w_conv, b_conv, y);

    // 4) out = y @ w_proj + b_proj (M=50176, K=384, N=384), fp32 out
    gemm_f32in<true><<<dim3(MTOT / BM, DIMC / BN), 256, 0, stream>>>(
        y, w_proj, b_proj, out, MTOT, DIMC, DIMC);
}

// Round 4
// 463.870 us; speedup vs baseline: 2.1245x; 1.3295x over previous
//
#include <hip/hip_runtime.h>
#include <cstdint>
#include <cstddef>

typedef __bf16 bf16x8 __attribute__((ext_vector_type(8)));
typedef float floatx4 __attribute__((ext_vector_type(4)));

#define DEV static __device__ __forceinline__

DEV float bf2f(uint16_t u) {
    union { uint32_t i; float f; } x; x.i = ((uint32_t)u) << 16; return x.f;
}
DEV uint16_t f2bf(float f) {
    uint32_t u = __float_as_uint(f);
    uint32_t r = (u + 0x7FFFu + ((u >> 16) & 1u)) >> 16;   // RNE
    return (uint16_t)r;
}
DEV bf16x8 as_bf8(uint4 u) {
    union { uint4 u; bf16x8 b; } c; c.u = u; return c.b;
}
// async global->LDS, 16B per lane. LDS dest must be wave-uniform base (+lane*16 by HW).
DEV void g2l16(const void* g, void* l) {
    __builtin_amdgcn_global_load_lds(
        (const __attribute__((address_space(1))) void*)g,
        (__attribute__((address_space(3))) void*)l, 16, 0, 0);
}

union U16x8 { uint16_t h[8]; uint4 u; };

// ---------------- problem constants ----------------
constexpr int DIMC  = 384;
constexpr int HEADS = 12;
constexpr int IMH   = 56, IMW = 56;
constexpr int NTOK  = IMH * IMW;        // 3136
constexpr int BATCH = 16;
constexpr int MTOT  = BATCH * NTOK;     // 50176
constexpr int QKVLD = 3 * DIMC;         // 1152
constexpr int GK    = 384;              // K for both GEMMs

// ---------------- prep: fp32 -> bf16 (8 elems/thread) ----------------
__global__ __launch_bounds__(256) void cvt_bf16(const float* __restrict__ in,
                                                uint16_t* __restrict__ out)
{
    size_t i = ((size_t)blockIdx.x * 256 + threadIdx.x) * 8;
    float4 a = *(const float4*)(in + i);
    float4 b = *(const float4*)(in + i + 4);
    U16x8 t;
    t.h[0] = f2bf(a.x); t.h[1] = f2bf(a.y); t.h[2] = f2bf(a.z); t.h[3] = f2bf(a.w);
    t.h[4] = f2bf(b.x); t.h[5] = f2bf(b.y); t.h[6] = f2bf(b.z); t.h[7] = f2bf(b.w);
    *(uint4*)(out + i) = t.u;
}

// ---------------- prep: in[R][C] fp32 -> out[C][R] bf16 ----------------
__global__ __launch_bounds__(256) void transpose_cvt(const float* __restrict__ in,
                                                     uint16_t* __restrict__ out,
                                                     int R, int C)
{
    int idx = blockIdx.x * 256 + threadIdx.x;   // output-linear: idx = c*R + r
    int r = idx % R, c = idx / R;
    out[idx] = f2bf(in[(size_t)r * C + c]);
}

// ---------------- GEMM (m97 structure): C[M,N] = A[M,K=384] @ Bt[N,K]^T ----
// A bf16 [M][384], Bt bf16 [N][384]; C bf16 (CF32=false) or fp32 (+bias).
template<bool CF32>
__global__ __launch_bounds__(256) void gemm_bt(const uint16_t* __restrict__ A,
                                               const uint16_t* __restrict__ Bt,
                                               const float* __restrict__ bias,
                                               void* __restrict__ Cptr,
                                               int N)
{
    __shared__ __align__(16) uint16_t sA[128 * 32];
    __shared__ __align__(16) uint16_t sB[128 * 32];

    const int t    = threadIdx.x;
    const int bm   = blockIdx.x, bn = blockIdx.y;
    const int wave = t >> 6, lane = t & 63;
    const int wm   = (wave >> 1) * 64, wn = (wave & 1) * 64;
    const int lr   = lane & 15, quad = lane >> 4;

    // staging: thread t covers row t>>2 (call1) / 64+(t>>2) (call2), 8 elems at (t&3)*8
    const uint16_t* Ag = A  + (size_t)(bm * 128 + (t >> 2)) * GK + (t & 3) * 8;
    const uint16_t* Bg = Bt + (size_t)(bn * 128 + (t >> 2)) * GK + (t & 3) * 8;
    uint16_t* lA1 = sA + wave * 512;
    uint16_t* lA2 = sA + 2048 + wave * 512;
    uint16_t* lB1 = sB + wave * 512;
    uint16_t* lB2 = sB + 2048 + wave * 512;

    floatx4 acc[4][4] = {};

    #pragma unroll
    for (int k0 = 0; k0 < GK; k0 += 32) {
        __syncthreads();
        g2l16(Ag + k0, lA1);
        g2l16(Ag + (size_t)64 * GK + k0, lA2);
        g2l16(Bg + k0, lB1);
        g2l16(Bg + (size_t)64 * GK + k0, lB2);
        __syncthreads();   // compiler emits s_waitcnt vmcnt(0) before barrier

        bf16x8 af[4], bfr[4];
        #pragma unroll
        for (int mt = 0; mt < 4; ++mt)
            af[mt] = *(const bf16x8*)&sA[(wm + mt * 16 + lr) * 32 + quad * 8];
        #pragma unroll
        for (int nt = 0; nt < 4; ++nt)
            bfr[nt] = *(const bf16x8*)&sB[(wn + nt * 16 + lr) * 32 + quad * 8];
        #pragma unroll
        for (int mt = 0; mt < 4; ++mt)
            #pragma unroll
            for (int nt = 0; nt < 4; ++nt)
                acc[mt][nt] = __builtin_amdgcn_mfma_f32_16x16x32_bf16(
                    af[mt], bfr[nt], acc[mt][nt], 0, 0, 0);
    }

    // epilogue: C/D layout col=lane&15, row=quad*4+reg
    #pragma unroll
    for (int mt = 0; mt < 4; ++mt) {
        #pragma unroll
        for (int nt = 0; nt < 4; ++nt) {
            int gc = bn * 128 + wn + nt * 16 + lr;
            float bv = bias ? bias[gc] : 0.0f;
            int gr0 = bm * 128 + wm + mt * 16 + quad * 4;
            #pragma unroll
            for (int i = 0; i < 4; ++i) {
                if constexpr (CF32) {
                    ((float*)Cptr)[(size_t)(gr0 + i) * N + gc] = acc[mt][nt][i] + bv;
                } else {
                    ((uint16_t*)Cptr)[(size_t)(gr0 + i) * N + gc] = f2bf(acc[mt][nt][i] + bv);
                }
            }
        }
    }
}

// ---------------- MFMA windowed attention ----------------
// one wave per (b, window, head); 2 waves / 128-thread block.
constexpr int PLD = 72;   // padded row stride (bf16 elems)

__global__ __launch_bounds__(128) void attn_mfma(const uint16_t* __restrict__ qkv,
                                                 uint16_t* __restrict__ y)
{
    __shared__ uint16_t lds[2][(64 + 32) * PLD];

    const int wave = threadIdx.x >> 6;
    const int lane = threadIdx.x & 63;
    const int unit = blockIdx.x * 2 + wave;          // 0..12287
    const int h  = unit % HEADS;
    const int w  = (unit / HEADS) & 63;
    const int b  = unit / (HEADS * 64);
    const int wy = w >> 3, wx = w & 7;
    const int lr = lane & 15, quad = lane >> 4;

    uint16_t* Pbuf = lds[wave];
    uint16_t* Vt   = lds[wave] + 64 * PLD;

    auto rowbase = [&](int i, int which) -> const uint16_t* {
        int py = i / 7, px = i % 7;
        int n = (wy * 7 + py) * IMW + wx * 7 + px;
        return qkv + (size_t)(b * NTOK + n) * QKVLD + which * DIMC + h * 32;
    };

    uint4 qf[4], kf[4];
    #pragma unroll
    for (int tm = 0; tm < 4; ++tm) {
        int i = tm * 16 + lr;
        if (i < 49) {
            qf[tm] = *(const uint4*)(rowbase(i, 0) + quad * 8);
            kf[tm] = *(const uint4*)(rowbase(i, 1) + quad * 8);
        } else {
            qf[tm] = uint4{0, 0, 0, 0};
            kf[tm] = uint4{0, 0, 0, 0};
        }
    }

    {   // stage V transposed: Vt[d][j]
        int j = lane;
        uint16_t vrow[32];
        if (j < 49) {
            const uint16_t* vr = rowbase(j, 2);
            #pragma unroll
            for (int p = 0; p < 4; ++p) {
                U16x8 tmp; tmp.u = *(const uint4*)(vr + p * 8);
                #pragma unroll
                for (int q = 0; q < 8; ++q) vrow[p * 8 + q] = tmp.h[q];
            }
        } else {
            #pragma unroll
            for (int d = 0; d < 32; ++d) vrow[d] = 0;
        }
        #pragma unroll
        for (int d = 0; d < 32; ++d) Vt[d * PLD + j] = vrow[d];
    }

    floatx4 S[4][4] = {};
    #pragma unroll
    for (int tm = 0; tm < 4; ++tm)
        #pragma unroll
        for (int tn = 0; tn < 4; ++tn)
            S[tm][tn] = __builtin_amdgcn_mfma_f32_16x16x32_bf16(
                as_bf8(qf[tm]), as_bf8(kf[tn]), S[tm][tn], 0, 0, 0);

    const float scale = 0.17677669529663687f;  // 32^-0.5
    const bool v3 = (lr == 0);
    #pragma unroll
    for (int tm = 0; tm < 4; ++tm) {
        #pragma unroll
        for (int i = 0; i < 4; ++i) {
            float e0 = __expf(S[tm][0][i] * scale);
            float e1 = __expf(S[tm][1][i] * scale);
            float e2 = __expf(S[tm][2][i] * scale);
            float e3 = v3 ? __expf(S[tm][3][i] * scale) : 0.0f;
            float s = e0 + e1 + e2 + e3;
            #pragma unroll
            for (int d = 1; d < 16; d <<= 1) s += __shfl_xor(s, d);
            float inv = 1.0f / s;
            int row = tm * 16 + quad * 4 + i;
            Pbuf[row * PLD + lr]      = f2bf(e0 * inv);
            Pbuf[row * PLD + 16 + lr] = f2bf(e1 * inv);
            Pbuf[row * PLD + 32 + lr] = f2bf(e2 * inv);
            Pbuf[row * PLD + 48 + lr] = f2bf(e3 * inv);
        }
    }

    floatx4 O[4][2] = {};
    #pragma unroll
    for (int kk = 0; kk < 2; ++kk) {
        bf16x8 pf[4], vf[2];
        #pragma unroll
        for (int tm = 0; tm < 4; ++tm)
            pf[tm] = *(const bf16x8*)&Pbuf[(tm * 16 + lr) * PLD + kk * 32 + quad * 8];
        #pragma unroll
        for (int tn = 0; tn < 2; ++tn)
            vf[tn] = *(const bf16x8*)&Vt[(tn * 16 + lr) * PLD + kk * 32 + quad * 8];
        #pragma unroll
        for (int tm = 0; tm < 4; ++tm)
            #pragma unroll
            for (int tn = 0; tn < 2; ++tn)
                O[tm][tn] = __builtin_amdgcn_mfma_f32_16x16x32_bf16(
                    pf[tm], vf[tn], O[tm][tn], 0, 0, 0);
    }

    #pragma unroll
    for (int tm = 0; tm < 4; ++tm) {
        #pragma unroll
        for (int i = 0; i < 4; ++i) {
            int r = tm * 16 + quad * 4 + i;
            if (r < 49) {
                int py = r / 7, px = r % 7;
                int n = (wy * 7 + py) * IMW + wx * 7 + px;
                uint16_t* dst = y + (size_t)(b * NTOK + n) * DIMC + h * 32;
                dst[lr]      = f2bf(O[tm][0][i]);
                dst[16 + lr] = f2bf(O[tm][1][i]);
            }
        }
    }
}

// ---------------- depthwise 3x3 conv on v, accumulate into y (bf16) --------
__global__ __launch_bounds__(256) void conv_kernel(const uint16_t* __restrict__ qkv,
                                                   const float* __restrict__ wconv,
                                                   const float* __restrict__ bconv,
                                                   uint16_t* __restrict__ y)
{
    size_t idx = (size_t)blockIdx.x * 256 + threadIdx.x;
    int c   = (int)(idx % DIMC);
    int rem = (int)(idx / DIMC);
    int n   = rem % NTOK;
    int b   = rem / NTOK;
    int y0 = n / IMW, x0 = n % IMW;

    float acc = bconv[c];
    #pragma unroll
    for (int ky = 0; ky < 3; ++ky) {
        int yy = y0 + ky - 1;
        if (yy < 0 || yy >= IMH) continue;
        #pragma unroll
        for (int kx = 0; kx < 3; ++kx) {
            int xx = x0 + kx - 1;
            if (xx < 0 || xx >= IMW) continue;
            float vv = bf2f(qkv[(size_t)(b * NTOK + yy * IMW + xx) * QKVLD + 2 * DIMC + c]);
            float wv = wconv[(ky * 3 + kx) * DIMC + c];
            acc += vv * wv;
        }
    }
    y[idx] = f2bf(bf2f(y[idx]) + acc);
}

// ---------------- launch ----------------
extern "C" void kernel_launch(void* const* d_in, const int* in_sizes, int n_in,
                              void* d_out, int out_size, void* d_ws, size_t ws_size,
                              hipStream_t stream)
{
    const float* x      = (const float*)d_in[0];
    const float* w_qkv  = (const float*)d_in[1];
    const float* w_proj = (const float*)d_in[2];
    const float* b_proj = (const float*)d_in[3];
    const float* w_conv = (const float*)d_in[4];
    const float* b_conv = (const float*)d_in[5];
    float* out = (float*)d_out;

    // ws layout (155.3 MB):
    //  [0, 115605504)              qkv bf16 (50176 x 1152)
    //  [115605504, +38535168)      xb bf16 (50176 x 384), reused as y bf16 after GEMM1
    //  then wqkvT bf16 (1152x384), wprojT bf16 (384x384)
    char* ws = (char*)d_ws;
    uint16_t* qkv    = (uint16_t*)ws;
    uint16_t* xb     = (uint16_t*)(ws + 115605504);
    uint16_t* yb     = xb;  // alias: xb dead after GEMM1
    uint16_t* wqkvT  = (uint16_t*)(ws + 115605504 + 38535168);
    uint16_t* wprojT = wqkvT + QKVLD * GK;

    // prep
    cvt_bf16<<<dim3((MTOT * DIMC) / (8 * 256)), 256, 0, stream>>>(x, xb);
    transpose_cvt<<<dim3((GK * QKVLD) / 256), 256, 0, stream>>>(w_qkv, wqkvT, GK, QKVLD);
    transpose_cvt<<<dim3((GK * DIMC) / 256), 256, 0, stream>>>(w_proj, wprojT, GK, DIMC);

    // 1) qkv = xb @ w_qkv   (M=50176, N=1152), bf16 out
    gemm_bt<false><<<dim3(MTOT / 128, QKVLD / 128), 256, 0, stream>>>(
        xb, wqkvT, nullptr, qkv, QKVLD);

    // 2) MFMA windowed attention -> y (bf16)
    attn_mfma<<<dim3(BATCH * 64 * HEADS / 2), 128, 0, stream>>>(qkv, yb);

    // 3) depthwise conv on v, y += v_lim
    conv_kernel<<<dim3((MTOT * DIMC) / 256), 256, 0, stream>>>(qkv, w_conv, b_conv, yb);

    // 4) out = y @ w_proj + b_proj (M=50176, N=384), fp32 out
    gemm_bt<true><<<dim3(MTOT / 128, DIMC / 128), 256, 0, stream>>>(
        yb, wprojT, b_proj, out, DIMC);
}